// Round 2
// baseline (491.962 us; speedup 1.0000x reference)
//
#include <hip/hip_runtime.h>
#include <hip/hip_bf16.h>

#define E_ 4
#define M_ 4096
#define D_ 1024
#define NIT 4
#define THRESH_ 0.01f

typedef __attribute__((ext_vector_type(8))) short bf16x8;
typedef __attribute__((ext_vector_type(4))) float f32x4;

__device__ inline unsigned short f2bf(float x) {
    unsigned u = __float_as_uint(x);
    unsigned r = (u + 0x7FFFu + ((u >> 16) & 1u)) >> 16;  // RNE
    return (unsigned short)r;
}

__device__ inline float Kf(float s) {            // K = exp(10*(sim-1))
    return __expf(fmaf(10.f, s, -10.f));
}

__device__ inline void unpack8(const int4& raw, float* s) {
    const unsigned* pu = reinterpret_cast<const unsigned*>(&raw);
#pragma unroll
    for (int j = 0; j < 4; ++j) {
        s[2*j]   = __uint_as_float(pu[j] << 16);
        s[2*j+1] = __uint_as_float(pu[j] & 0xFFFF0000u);
    }
}

// ---------------- normalize rows + convert to bf16 ----------------
__global__ __launch_bounds__(256)
void normalize_bf16(const float* __restrict__ g, const float* __restrict__ f,
                    __hip_bfloat16* __restrict__ Sb, __hip_bfloat16* __restrict__ Tb)
{
    const int w = threadIdx.x >> 6, l = threadIdx.x & 63;
    const size_t row = (size_t)blockIdx.x * 4 + w;       // 0..E*M-1
    const float* src = (blockIdx.y == 0 ? g : f) + row * (size_t)D_;
    __hip_bfloat16* dst = (blockIdx.y == 0 ? Sb : Tb) + row * (size_t)D_;
    float4 v[4];
    float ss = 0.f;
#pragma unroll
    for (int i = 0; i < 4; ++i) {
        v[i] = *(const float4*)(src + (i*64 + l) * 4);
        ss += v[i].x*v[i].x + v[i].y*v[i].y + v[i].z*v[i].z + v[i].w*v[i].w;
    }
#pragma unroll
    for (int off = 32; off; off >>= 1) ss += __shfl_xor(ss, off);
    const float inv = 1.f / fmaxf(sqrtf(ss), 1e-12f);
#pragma unroll
    for (int i = 0; i < 4; ++i) {
        ushort4 o;
        o.x = f2bf(v[i].x * inv); o.y = f2bf(v[i].y * inv);
        o.z = f2bf(v[i].z * inv); o.w = f2bf(v[i].w * inv);
        *(ushort4*)((unsigned short*)dst + (i*64 + l) * 4) = o;
    }
}

// ---------------- bf16 NT-GEMM: sim = S @ T^T, epilogue also Kc0 = K @ 1 ----------------
__global__ __launch_bounds__(256)
void gemm_bt(const __hip_bfloat16* __restrict__ Sb, const __hip_bfloat16* __restrict__ Tb,
             __hip_bfloat16* __restrict__ sim, float* __restrict__ Kc0)
{
    const int e = blockIdx.z;
    const int brow = blockIdx.y, bcol = blockIdx.x;
    const int t = threadIdx.x, w = t >> 6, l = t & 63;
    const int wr = w >> 1, wc = w & 1;

    __shared__ __hip_bfloat16 Asl[128*32];
    __shared__ __hip_bfloat16 Bsl[128*32];

    const __hip_bfloat16* Ag = Sb + ((size_t)e*M_ + (size_t)brow*128) * D_;
    const __hip_bfloat16* Bg = Tb + ((size_t)e*M_ + (size_t)bcol*128) * D_;

    f32x4 acc[4][4] = {};

    for (int k0 = 0; k0 < D_; k0 += 32) {
#pragma unroll
        for (int i = 0; i < 2; ++i) {
            const int ci = i*256 + t;                 // 16B chunk id 0..511
            const int row = ci >> 2, c16 = ci & 3;
            const size_t goff = (size_t)row * D_ + k0 + c16*8;
            __builtin_amdgcn_global_load_lds(
                (const __attribute__((address_space(1))) void*)(Ag + goff),
                (__attribute__((address_space(3))) void*)(Asl + ci*8), 16, 0, 0);
            __builtin_amdgcn_global_load_lds(
                (const __attribute__((address_space(1))) void*)(Bg + goff),
                (__attribute__((address_space(3))) void*)(Bsl + ci*8), 16, 0, 0);
        }
        __syncthreads();
        bf16x8 af[4], bfr[4];
#pragma unroll
        for (int m = 0; m < 4; ++m)
            af[m] = *(const bf16x8*)(Asl + (wr*64 + m*16 + (l & 15)) * 32 + (l >> 4) * 8);
#pragma unroll
        for (int n = 0; n < 4; ++n)
            bfr[n] = *(const bf16x8*)(Bsl + (wc*64 + n*16 + (l & 15)) * 32 + (l >> 4) * 8);
#pragma unroll
        for (int m = 0; m < 4; ++m)
#pragma unroll
            for (int n = 0; n < 4; ++n)
                acc[m][n] = __builtin_amdgcn_mfma_f32_16x16x32_bf16(af[m], bfr[n], acc[m][n], 0, 0, 0);
        __syncthreads();
    }

    // C/D layout: col = lane&15, row = (lane>>4)*4 + reg
    unsigned short* Cg = (unsigned short*)(sim + (size_t)e*M_*M_);
    float* kc = Kc0 + e*M_;
    const size_t crow0 = (size_t)brow*128 + wr*64;
    const int ccol0 = bcol*128 + wc*64;
#pragma unroll
    for (int m = 0; m < 4; ++m)
#pragma unroll
        for (int j = 0; j < 4; ++j) {
            const size_t r = crow0 + m*16 + (l >> 4)*4 + j;
            float rs = 0.f;
#pragma unroll
            for (int n = 0; n < 4; ++n) {
                const float val = acc[m][n][j];
                Cg[r * M_ + ccol0 + n*16 + (l & 15)] = f2bf(val);
                rs += Kf(val);
            }
            rs += __shfl_xor(rs, 1);
            rs += __shfl_xor(rs, 2);
            rs += __shfl_xor(rs, 4);
            rs += __shfl_xor(rs, 8);
            if ((l & 15) == 0) atomicAdd(&kc[r], rs);
        }
}

// ---------------- r update for it=0 from GEMM-fused Kc0 ----------------
__global__ __launch_bounds__(256)
void r_update0(const float* __restrict__ Kc0, float* __restrict__ r_cur,
               float* __restrict__ err)
{
    const int e = blockIdx.y;
    const int i = blockIdx.x * 256 + threadIdx.x;
    const float newr = (1.0f / M_) / Kc0[e*M_ + i];
    const float oldr = r_cur[e*M_ + i];              // = 1.0 from init
    r_cur[e*M_ + i] = newr;
    float d = fabsf(newr - oldr);
#pragma unroll
    for (int off = 32; off; off >>= 1) d += __shfl_down(d, off);
    __shared__ float bl[4];
    if ((threadIdx.x & 63) == 0) bl[threadIdx.x >> 6] = d;
    __syncthreads();
    if (threadIdx.x == 0) atomicAdd(&err[0*E_ + e], bl[0]+bl[1]+bl[2]+bl[3]);
}

// ---------------- it>=1: Kc[m] = sum_n K(sim)*c[n]; fused r update + err ----------------
__global__ __launch_bounds__(256)
void kc_rowmv(const __hip_bfloat16* __restrict__ sim, const float* __restrict__ c_cur,
              float* __restrict__ r_cur, float* __restrict__ err,
              const int* __restrict__ run, int it)
{
    const int e = blockIdx.y;
    if (!run[it*E_ + e]) return;
    const int w = threadIdx.x >> 6, l = threadIdx.x & 63;
    const int row = blockIdx.x * 4 + w;
    const unsigned short* rp = (const unsigned short*)sim + ((size_t)e*M_ + row) * M_;
    const float* cp = c_cur + e*M_;
    float p = 0.f;
#pragma unroll
    for (int i = 0; i < 8; ++i) {
        const int col = (i*64 + l) * 8;
        int4 raw = *(const int4*)(rp + col);
        float4 ca = *(const float4*)(cp + col);
        float4 cb = *(const float4*)(cp + col + 4);
        float s[8]; unpack8(raw, s);
        p += Kf(s[0])*ca.x + Kf(s[1])*ca.y + Kf(s[2])*ca.z + Kf(s[3])*ca.w
           + Kf(s[4])*cb.x + Kf(s[5])*cb.y + Kf(s[6])*cb.z + Kf(s[7])*cb.w;
    }
#pragma unroll
    for (int off = 32; off; off >>= 1) p += __shfl_down(p, off);
    __shared__ float bl[4];
    if (l == 0) {
        const float newr = (1.0f / M_) / p;
        const float oldr = r_cur[e*M_ + row];
        r_cur[e*M_ + row] = newr;
        bl[w] = fabsf(newr - oldr);
    }
    __syncthreads();
    if (threadIdx.x == 0) atomicAdd(&err[it*E_ + e], bl[0]+bl[1]+bl[2]+bl[3]);
}

// ---- partial[mc][n] = sum_{m in 64-chunk} K*r[m]; wpart = sum K*r[m]*s ----
__global__ __launch_bounds__(256)
void kt_colmv(const __hip_bfloat16* __restrict__ sim, const float* __restrict__ r_cur,
              float* __restrict__ part, float* __restrict__ wpart,
              const int* __restrict__ run, int it)
{
    const int e = blockIdx.z;
    if (!run[it*E_ + e]) return;
    const int mc = blockIdx.y;                           // 0..63
    const int n0 = blockIdx.x * 2048 + threadIdx.x * 8;
    __shared__ float rsh[64];
    if (threadIdx.x < 64) rsh[threadIdx.x] = r_cur[e*M_ + mc*64 + threadIdx.x];
    __syncthreads();
    const unsigned short* base = (const unsigned short*)sim + ((size_t)e*M_ + (size_t)mc*64) * M_ + n0;
    float acc[8] = {0.f,0.f,0.f,0.f,0.f,0.f,0.f,0.f};
    float wacc[8] = {0.f,0.f,0.f,0.f,0.f,0.f,0.f,0.f};
#pragma unroll 4
    for (int m = 0; m < 64; ++m) {
        const float rm = rsh[m];
        int4 raw = *(const int4*)(base + (size_t)m * M_);
        float s[8]; unpack8(raw, s);
#pragma unroll
        for (int j = 0; j < 8; ++j) {
            const float k = Kf(s[j]);
            acc[j]  = fmaf(rm, k, acc[j]);
            wacc[j] = fmaf(rm, k * s[j], wacc[j]);
        }
    }
    const size_t po = (size_t)(e*64 + mc) * M_ + n0;
    float4 o0 = {acc[0], acc[1], acc[2], acc[3]};
    float4 o1 = {acc[4], acc[5], acc[6], acc[7]};
    *(float4*)(part + po) = o0;
    *(float4*)(part + po + 4) = o1;
    float4 w0 = {wacc[0], wacc[1], wacc[2], wacc[3]};
    float4 w1 = {wacc[4], wacc[5], wacc[6], wacc[7]};
    *(float4*)(wpart + po) = w0;
    *(float4*)(wpart + po + 4) = w1;
}

// ---- c = v/colsum; fused per-iteration loss = sum_n c[n]*wsum[n]; fused flag ----
__global__ __launch_bounds__(256)
void c_update(const float* __restrict__ part, const float* __restrict__ wpart,
              float* __restrict__ c_cur, const float* __restrict__ err,
              float* __restrict__ loss, int* __restrict__ run, int it)
{
    const int e = blockIdx.y;
    const int active = run[it*E_ + e];
    if (blockIdx.x == 0 && threadIdx.x == 0)
        run[(it+1)*E_ + e] = active && (err[it*E_ + e] * (1.0f / M_) >= THRESH_);
    if (!active) return;
    const int n = blockIdx.x * 256 + threadIdx.x;
    float s = 0.f, ws = 0.f;
#pragma unroll
    for (int mc = 0; mc < 64; ++mc) {
        const size_t po = (size_t)(e*64 + mc) * M_ + n;
        s += part[po];
        ws += wpart[po];
    }
    const float c = (1.0f / M_) / s;
    c_cur[e*M_ + n] = c;
    float lp = c * ws;
#pragma unroll
    for (int off = 32; off; off >>= 1) lp += __shfl_down(lp, off);
    __shared__ float bl[4];
    if ((threadIdx.x & 63) == 0) bl[threadIdx.x >> 6] = lp;
    __syncthreads();
    if (threadIdx.x == 0) atomicAdd(&loss[it*E_ + e], bl[0]+bl[1]+bl[2]+bl[3]);
}

// ---------------- init + final weighting ----------------
__global__ void init_rc(float* __restrict__ r_cur, int* __restrict__ run)
{
    const int i = blockIdx.x * 256 + threadIdx.x;
    if (i < E_*M_) r_cur[i] = 1.f;
    if (i < E_) run[i] = 1;
}

__global__ void finalize(const float* __restrict__ loss, const int* __restrict__ run,
                         const float* __restrict__ prev, float* __restrict__ out)
{
    if (threadIdx.x == 0 && blockIdx.x == 0) {
        float l[E_], wgt[E_], sw = 0.f, tot = 0.f;
        for (int e = 0; e < E_; ++e) {
            l[e] = 0.f;
            for (int it = 0; it < NIT; ++it)
                if (run[it*E_ + e]) l[e] = loss[it*E_ + e];   // last active iteration
            wgt[e] = expf(l[e] / (prev[e] + 1e-8f));
            sw += wgt[e];
        }
        for (int e = 0; e < E_; ++e) tot += (wgt[e] / sw * (float)E_) * l[e];
        out[0] = tot;
    }
}

extern "C" void kernel_launch(void* const* d_in, const int* in_sizes, int n_in,
                              void* d_out, int out_size, void* d_ws, size_t ws_size,
                              hipStream_t stream)
{
    (void)in_sizes; (void)n_in; (void)out_size; (void)ws_size;
    const float* gts   = (const float*)d_in[0];
    const float* feats = (const float*)d_in[1];
    const float* prev  = (const float*)d_in[2];
    float* out = (float*)d_out;
    char* ws = (char*)d_ws;

    __hip_bfloat16* sim = (__hip_bfloat16*)ws;                       // 134,217,728 B
    __hip_bfloat16* Sb  = (__hip_bfloat16*)(ws + 134217728);         //  33,554,432 B
    __hip_bfloat16* Tb  = (__hip_bfloat16*)(ws + 167772160);         //  33,554,432 B
    float* part  = (float*)(ws + 201326592);                         //   4,194,304 B (64 chunks)
    float* wpart = (float*)(ws + 205520896);                         //   4,194,304 B
    float* Kc0   = (float*)(ws + 209715200);                         //      65,536 B
    float* r_cur = (float*)(ws + 209780736);                         //      65,536 B
    float* c_cur = (float*)(ws + 209846272);                         //      65,536 B
    float* err   = (float*)(ws + 209911808);                         //          64 B
    float* loss  = (float*)(ws + 209911872);                         //          64 B
    int*   run   = (int*)  (ws + 209911936);                         //          80 B

    hipMemsetAsync(err, 0, 224, stream);              // err + loss + run
    hipMemsetAsync(Kc0, 0, E_*M_*sizeof(float), stream);
    init_rc<<<dim3(64), 256, 0, stream>>>(r_cur, run);
    normalize_bf16<<<dim3(E_*M_/4, 2), 256, 0, stream>>>(gts, feats, Sb, Tb);
    gemm_bt<<<dim3(32, 32, E_), 256, 0, stream>>>(Sb, Tb, sim, Kc0);

    // it = 0 (row matvec fused into GEMM epilogue)
    r_update0<<<dim3(M_/256, E_), 256, 0, stream>>>(Kc0, r_cur, err);
    kt_colmv<<<dim3(2, 64, E_), 256, 0, stream>>>(sim, r_cur, part, wpart, run, 0);
    c_update<<<dim3(M_/256, E_), 256, 0, stream>>>(part, wpart, c_cur, err, loss, run, 0);

    for (int it = 1; it < NIT; ++it) {
        kc_rowmv<<<dim3(M_/4, E_), 256, 0, stream>>>(sim, c_cur, r_cur, err, run, it);
        kt_colmv<<<dim3(2, 64, E_), 256, 0, stream>>>(sim, r_cur, part, wpart, run, it);
        c_update<<<dim3(M_/256, E_), 256, 0, stream>>>(part, wpart, c_cur, err, loss, run, it);
    }
    finalize<<<1, 64, 0, stream>>>(loss, run, prev, out);
}